// Round 12
// baseline (361.652 us; speedup 1.0000x reference)
//
#include <hip/hip_runtime.h>

// Problem geometry (from reference):
//   COMPRESSED_SHAPE = (8192, 64, 128) int4 -> N_UNPACKED = 67,108,864
//   N_PACKED = 33,554,432 packed bytes, each stored as ONE int32 in [0,256)
//   scale/zero_point: (8192*64) fp32, one per group of 128 unpacked values
//   d_out: FLOAT32 (fp16 ref -> "else float*"), 67,108,864 floats (256 MiB).
//   R6 PASS 369us (stride-32 dual stores). R11 PASS 359us (dense int2->float4).
//   Headline decomposition: ~250us fixed harness replay (1GiB ws poison 165us
//   + out poison ~41us + input restore ~44us) -> kernel ~100-110us ~= 3.7TB/s,
//   below the ~6.3TB/s copy ceiling (floor ~64us for 407MB).
//   This round: manual unroll x4 — issue 4 independent nt loads back-to-back
//   before any use (4x memory-level parallelism; rolled grid-stride loop
//   likely had 1 outstanding load/wave). Exact trip: NPAIR = 8 * 4 * stride.
#define N_PACKED_BYTES (8192 * 64 * 64)      // 33,554,432
#define NPAIR (N_PACKED_BYTES / 2)           // 16,777,216 int32-pairs -> one float4 each

typedef int   vi2 __attribute__((ext_vector_type(2)));
typedef float vf4 __attribute__((ext_vector_type(4)));

static __device__ __forceinline__ vf4 dq(vi2 wv, float s, float z) {
    vf4 o;
    o.x = fmaf((float)(wv.x & 0xF), s, z);
    o.y = fmaf((float)((wv.x >> 4) & 0xF), s, z);
    o.z = fmaf((float)(wv.y & 0xF), s, z);
    o.w = fmaf((float)((wv.y >> 4) & 0xF), s, z);
    return o;
}

__global__ __launch_bounds__(256) void dequant_int4_kernel(
    const vi2* __restrict__ w,         // 2 packed bytes (as 2 int32) per pair
    const float* __restrict__ scale,   // (8192*64)
    const float* __restrict__ zp,      // (8192*64)
    vf4* __restrict__ out)             // 1 dense float4 per pair
{
    const int tid    = blockIdx.x * blockDim.x + threadIdx.x;
    const int stride = gridDim.x * blockDim.x;            // 524,288
    // pair p covers unpacked flat [4p,4p+4) -> group = p/32
    for (int base = tid; base < NPAIR; base += 4 * stride) {
        const int p0 = base;
        const int p1 = base + stride;
        const int p2 = base + 2 * stride;
        const int p3 = base + 3 * stride;

        // 4 independent loads issued before any consumer -> 4x MLP
        const vi2 w0 = __builtin_nontemporal_load(&w[p0]);
        const vi2 w1 = __builtin_nontemporal_load(&w[p1]);
        const vi2 w2 = __builtin_nontemporal_load(&w[p2]);
        const vi2 w3 = __builtin_nontemporal_load(&w[p3]);

        const float s0 = scale[p0 >> 5], z0 = zp[p0 >> 5];
        const float s1 = scale[p1 >> 5], z1 = zp[p1 >> 5];
        const float s2 = scale[p2 >> 5], z2 = zp[p2 >> 5];
        const float s3 = scale[p3 >> 5], z3 = zp[p3 >> 5];

        __builtin_nontemporal_store(dq(w0, s0, z0), &out[p0]);
        __builtin_nontemporal_store(dq(w1, s1, z1), &out[p1]);
        __builtin_nontemporal_store(dq(w2, s2, z2), &out[p2]);
        __builtin_nontemporal_store(dq(w3, s3, z3), &out[p3]);
    }
}

extern "C" void kernel_launch(void* const* d_in, const int* in_sizes, int n_in,
                              void* d_out, int out_size, void* d_ws, size_t ws_size,
                              hipStream_t stream) {
    const vi2*   w     = (const vi2*)d_in[0];
    const float* scale = (const float*)d_in[1];
    const float* zp    = (const float*)d_in[2];
    vf4* out = (vf4*)d_out;

    // 2048 blocks x 256 threads = 524,288 threads; NPAIR = 8 * (4*524,288) exact.
    const int blocks = 2048;
    dequant_int4_kernel<<<blocks, 256, 0, stream>>>(w, scale, zp, out);
}